// Round 7
// baseline (250.724 us; speedup 1.0000x reference)
//
#include <hip/hip_runtime.h>
#include <hip/hip_bf16.h>

#define D 128
#define LOSS_MARGIN 0.2f
#define SPB 25                 // 16-col MFMA steps per block
#define SLAB (SPB * 16)        // 400 cols; C = 250 slabs * 400
#define ROWG 8                 // 2048 / 256 row-groups
#define CHUNK_BYTES 20480      // 80 cols * 256 B

typedef __attribute__((ext_vector_type(8))) short bf16x8;
typedef __attribute__((ext_vector_type(4))) float f32x4;

static __device__ __forceinline__ unsigned short f2bf(float f) {
    unsigned u = __float_as_uint(f);
    unsigned r = (u + 0x7FFFu + ((u >> 16) & 1u)) >> 16;  // RNE
    return (unsigned short)r;
}

// async global->LDS, 16B per lane; LDS dest wave-uniform base (HW adds lane*16).
static __device__ __forceinline__ void stage16(const void* g, void* l) {
    __builtin_amdgcn_global_load_lds(
        (__attribute__((address_space(1))) void*)g,
        (__attribute__((address_space(3))) void*)l, 16, 0, 0);
}

// Pass A: L2-normalize proxies -> bf16 (XOR-swizzled rows); embeddings -> bf16.
// Swizzle: within each 256B row, 16B slot at byte b stored at b ^ ((row&7)<<4).
// Also initializes minneg sentinels, loss accumulator, finalize ticket.
__global__ void prep_kernel(const float* __restrict__ prox,
                            const float* __restrict__ emb,
                            unsigned short* __restrict__ pn,
                            unsigned short* __restrict__ en,
                            unsigned int* __restrict__ minneg,
                            float* __restrict__ accum,
                            unsigned int* __restrict__ ticket,
                            int C, int B) {
    unsigned gtid = blockIdx.x * blockDim.x + threadIdx.x;
    if (gtid < (unsigned)B) minneg[gtid] = 0xFFFFFFFFu;
    if (gtid == 0) { *accum = 0.f; *ticket = 0u; }

    int wave = blockIdx.x * (blockDim.x >> 6) + (threadIdx.x >> 6);
    int lane = threadIdx.x & 63;
    int half = lane >> 5;
    int l32  = lane & 31;
    int row = wave * 2 + half;
    if (row >= C + B) return;

    if (row < C) {
        float4 v = *(const float4*)(prox + (size_t)row * D + l32 * 4);
        float ss = v.x * v.x + v.y * v.y + v.z * v.z + v.w * v.w;
        #pragma unroll
        for (int m = 1; m < 32; m <<= 1) ss += __shfl_xor(ss, m);
        float scale = rsqrtf(ss);
        uint2 pack;
        pack.x = (unsigned)f2bf(v.x * scale) | ((unsigned)f2bf(v.y * scale) << 16);
        pack.y = (unsigned)f2bf(v.z * scale) | ((unsigned)f2bf(v.w * scale) << 16);
        unsigned off = (unsigned)(l32 * 8) ^ (((unsigned)row & 7u) << 4);
        *(uint2*)((char*)(pn + (size_t)row * D) + off) = pack;
    } else {
        int r = row - C;
        float4 v = *(const float4*)(emb + (size_t)r * D + l32 * 4);
        uint2 pack;
        pack.x = (unsigned)f2bf(v.x) | ((unsigned)f2bf(v.y) << 16);
        pack.y = (unsigned)f2bf(v.z) | ((unsigned)f2bf(v.w) << 16);
        *(uint2*)(en + (size_t)r * D + l32 * 4) = pack;
    }
}

// Pass B: fused bf16 GEMM + per-row max over negatives.
// XCD-swizzled 1-D grid (2000 blocks). Block = 4 waves, 256 rows; slab 400 cols.
// B double-buffered in LDS via global_load_lds; fully unrolled 5-phase schedule
// so every ds_read_b128 is base-reg + immediate offset (zero addr VALU).
__global__ __launch_bounds__(256, 4) void gemmmax_kernel(
        const unsigned short* __restrict__ en,
        const unsigned short* __restrict__ pn,
        const int* __restrict__ labels,
        unsigned int* __restrict__ minneg) {
    __shared__ char smem[2 * CHUNK_BYTES];   // 40 KiB -> 4 blocks/CU

    int n = blockIdx.x;
    int chunkg = gridDim.x >> 3;             // 250 per XCD
    int wgid = (n & 7) * chunkg + (n >> 3);
    int slab   = wgid >> 3;
    int rowgrp = wgid & (ROWG - 1);

    int lane = threadIdx.x & 63;
    int wid  = threadIdx.x >> 6;
    int wbase = rowgrp * 256 + wid * 64;
    int r16 = lane & 15;
    int g   = lane >> 4;
    int col0 = slab * SLAB;
    int swz = (r16 & 7) << 4;

    const char* slabSrc = (const char*)pn + (size_t)col0 * (D * 2);
    int stago = wid * 1024 + lane * 16;

#define STAGE_CHUNK(T, BUF)                                                     \
    {                                                                           \
        const char* gs_ = slabSrc + (size_t)((T) * CHUNK_BYTES) + stago;        \
        char* ls_ = smem + (BUF) * CHUNK_BYTES + wid * 1024;                    \
        stage16(gs_,          ls_);                                             \
        stage16(gs_ + 4096,   ls_ + 4096);                                      \
        stage16(gs_ + 8192,   ls_ + 8192);                                      \
        stage16(gs_ + 12288,  ls_ + 12288);                                     \
        stage16(gs_ + 16384,  ls_ + 16384);                                     \
    }

    STAGE_CHUNK(0, 0)

    // A fragments: lane l, slot j -> E[row = wbase+s4*16+(l&15)][k = k4*32+(l>>4)*8+j]
    bf16x8 a[4][4];
    #pragma unroll
    for (int s4 = 0; s4 < 4; ++s4)
        #pragma unroll
        for (int k4 = 0; k4 < 4; ++k4)
            a[s4][k4] = *(const bf16x8*)(en + (size_t)(wbase + s4 * 16 + r16) * D + k4 * 32 + g * 8);

    // wave-uniform bitmask of steps containing a positive class
    unsigned bits = 0;
    #pragma unroll
    for (int s4 = 0; s4 < 4; ++s4)
        #pragma unroll
        for (int i = 0; i < 4; ++i) {
            int lb = labels[wbase + s4 * 16 + g * 4 + i];
            int pc = lb - col0;
            if (pc >= 0 && pc < SLAB) bits |= 1u << (pc >> 4);
        }
    #pragma unroll
    for (int m = 1; m < 64; m <<= 1) bits |= __shfl_xor(bits, m);
    unsigned sbits = __builtin_amdgcn_readfirstlane(bits);

    float rm[4][4];
    #pragma unroll
    for (int s4 = 0; s4 < 4; ++s4)
        #pragma unroll
        for (int i = 0; i < 4; ++i) rm[s4][i] = -1e30f;

    const f32x4 zero = {0.f, 0.f, 0.f, 0.f};
    // per-lane LDS base pointers; all step/buffer offsets are immediates
    const char* p0 = smem + r16 * 256 + ((g * 16 + 0)   ^ swz);
    const char* p1 = smem + r16 * 256 + ((g * 16 + 64)  ^ swz);
    const char* p2 = smem + r16 * 256 + ((g * 16 + 128) ^ swz);
    const char* p3 = smem + r16 * 256 + ((g * 16 + 192) ^ swz);

#define MFMA __builtin_amdgcn_mfma_f32_16x16x32_bf16
#define DO_STEP(BASE, STEP)                                                     \
    {                                                                           \
        bf16x8 b0 = *(const bf16x8*)(p0 + (BASE));                              \
        bf16x8 b1 = *(const bf16x8*)(p1 + (BASE));                              \
        bf16x8 b2 = *(const bf16x8*)(p2 + (BASE));                              \
        bf16x8 b3 = *(const bf16x8*)(p3 + (BASE));                              \
        f32x4 cc[4];                                                            \
        _Pragma("unroll")                                                       \
        for (int s4 = 0; s4 < 4; ++s4) cc[s4] = MFMA(a[s4][0], b0, zero, 0, 0, 0); \
        _Pragma("unroll")                                                       \
        for (int s4 = 0; s4 < 4; ++s4) cc[s4] = MFMA(a[s4][1], b1, cc[s4], 0, 0, 0); \
        _Pragma("unroll")                                                       \
        for (int s4 = 0; s4 < 4; ++s4) cc[s4] = MFMA(a[s4][2], b2, cc[s4], 0, 0, 0); \
        _Pragma("unroll")                                                       \
        for (int s4 = 0; s4 < 4; ++s4) cc[s4] = MFMA(a[s4][3], b3, cc[s4], 0, 0, 0); \
        if (__builtin_expect((sbits >> (STEP)) & 1u, 0)) {                      \
            int colg = col0 + (STEP) * 16 + r16;                                \
            _Pragma("unroll")                                                   \
            for (int s4 = 0; s4 < 4; ++s4)                                      \
                _Pragma("unroll")                                               \
                for (int i = 0; i < 4; ++i) {                                   \
                    int lb2 = labels[wbase + s4 * 16 + g * 4 + i];              \
                    float v = (colg == lb2) ? -1e30f : cc[s4][i];               \
                    rm[s4][i] = fmaxf(rm[s4][i], v);                            \
                }                                                               \
        } else {                                                                \
            _Pragma("unroll")                                                   \
            for (int s4 = 0; s4 < 4; ++s4)                                      \
                _Pragma("unroll")                                               \
                for (int i = 0; i < 4; ++i)                                     \
                    rm[s4][i] = fmaxf(rm[s4][i], cc[s4][i]);                    \
        }                                                                       \
    }

#define STEPS5(BASE, T0)                                                        \
    DO_STEP((BASE) + 0,     (T0) + 0)                                           \
    DO_STEP((BASE) + 4096,  (T0) + 1)                                           \
    DO_STEP((BASE) + 8192,  (T0) + 2)                                           \
    DO_STEP((BASE) + 12288, (T0) + 3)                                           \
    DO_STEP((BASE) + 16384, (T0) + 4)

    __syncthreads();                       // chunk 0 resident
    STAGE_CHUNK(1, 1) STEPS5(0, 0)              __syncthreads();
    STAGE_CHUNK(2, 0) STEPS5(CHUNK_BYTES, 5)    __syncthreads();
    STAGE_CHUNK(3, 1) STEPS5(0, 10)             __syncthreads();
    STAGE_CHUNK(4, 0) STEPS5(CHUNK_BYTES, 15)   __syncthreads();
    STEPS5(0, 20)
#undef STEPS5
#undef DO_STEP
#undef MFMA
#undef STAGE_CHUNK

    // reduce max across the 16 lanes of each row-group, combine across blocks
    #pragma unroll
    for (int s4 = 0; s4 < 4; ++s4)
        #pragma unroll
        for (int i = 0; i < 4; ++i) {
            float v = rm[s4][i];
            v = fmaxf(v, __shfl_xor(v, 1));
            v = fmaxf(v, __shfl_xor(v, 2));
            v = fmaxf(v, __shfl_xor(v, 4));
            v = fmaxf(v, __shfl_xor(v, 8));
            if (r16 == 0) {
                int r = wbase + s4 * 16 + g * 4 + i;
                float md = fmaxf(2.f - 2.f * v, 0.f);  // >=0 -> uint order == float order
                atomicMin(minneg + r, __float_as_uint(md));
            }
        }
}

// Pass C: exact fp32 positive distance + per-row loss; last block writes the mean.
__global__ void finalize_kernel(const float* __restrict__ emb,
                                const float* __restrict__ prox,
                                const int* __restrict__ labels,
                                const unsigned int* __restrict__ minneg,
                                float* __restrict__ accum,
                                unsigned int* __restrict__ ticket,
                                float* __restrict__ out, int B) {
    int wave = blockIdx.x * (blockDim.x >> 6) + (threadIdx.x >> 6);
    int lane = threadIdx.x & 63;
    if (wave < B) {
        int lab = labels[wave];
        float2 e = *(const float2*)(emb + (size_t)wave * D + lane * 2);
        float2 p = *(const float2*)(prox + (size_t)lab * D + lane * 2);
        float spp = p.x * p.x + p.y * p.y;
        float sep = e.x * p.x + e.y * p.y;
        #pragma unroll
        for (int m = 1; m < 64; m <<= 1) {
            spp += __shfl_xor(spp, m);
            sep += __shfl_xor(sep, m);
        }
        if (lane == 0) {
            float pos_sim = sep * rsqrtf(spp);
            float pos_dist = 2.f - 2.f * pos_sim;
            float mn = __uint_as_float(minneg[wave]);
            float loss = fmaxf(pos_dist + LOSS_MARGIN - mn, 0.f);
            atomicAdd(accum, loss);
        }
    }
    __threadfence();
    __syncthreads();
    if (threadIdx.x == 0) {
        unsigned old = atomicAdd(ticket, 1u);
        if (old == gridDim.x - 1) {            // last block: all adds visible
            __threadfence();
            float total = atomicAdd(accum, 0.f);   // coherent read
            out[0] = total * (1.f / (float)B);
        }
    }
}

extern "C" void kernel_launch(void* const* d_in, const int* in_sizes, int n_in,
                              void* d_out, int out_size, void* d_ws, size_t ws_size,
                              hipStream_t stream) {
    const float* emb  = (const float*)d_in[0];
    const float* prox = (const float*)d_in[1];
    const int*   labels = (const int*)d_in[2];
    int B = in_sizes[0] / D;  // 2048
    int C = in_sizes[1] / D;  // 100000

    char* ws = (char*)d_ws;
    unsigned short* pn = (unsigned short*)ws;                       // C*D bf16 (swizzled rows)
    size_t offEN  = (size_t)C * D * 2 + (size_t)64 * D * 2;
    unsigned short* en = (unsigned short*)(ws + offEN);             // B*D bf16
    size_t offMIN = offEN + (size_t)B * D * 2;
    unsigned int* minneg = (unsigned int*)(ws + offMIN);            // B u32
    size_t offACC = offMIN + (size_t)B * 4;
    float* accum = (float*)(ws + offACC);                           // 1 f32
    unsigned int* ticket = (unsigned int*)(ws + offACC + 64);       // 1 u32

    int totalRows = C + B;
    int prepWaves = (totalRows + 1) / 2;
    prep_kernel<<<dim3((prepWaves + 3) / 4), dim3(256), 0, stream>>>(
        prox, emb, pn, en, minneg, accum, ticket, C, B);
    gemmmax_kernel<<<dim3((B / 256) * (C / SLAB)), dim3(256), 0, stream>>>(
        en, pn, labels, minneg);
    finalize_kernel<<<dim3((B + 3) / 4), dim3(256), 0, stream>>>(
        emb, prox, labels, minneg, accum, ticket, (float*)d_out, B);
}

// Round 9
// 203.271 us; speedup vs baseline: 1.2334x; 1.2334x over previous
//
#include <hip/hip_runtime.h>
#include <hip/hip_bf16.h>

#define D 128
#define LOSS_MARGIN 0.2f
#define SPB 25                 // 16-col MFMA steps per block
#define SLAB (SPB * 16)        // 400 cols; C = 250 slabs * 400
#define ROWG 8                 // 2048 / 256 row-groups
#define CHUNK_BYTES 20480      // 80 cols * 256 B

typedef __attribute__((ext_vector_type(8))) short bf16x8;
typedef __attribute__((ext_vector_type(4))) float f32x4;

static __device__ __forceinline__ unsigned short f2bf(float f) {
    unsigned u = __float_as_uint(f);
    unsigned r = (u + 0x7FFFu + ((u >> 16) & 1u)) >> 16;  // RNE
    return (unsigned short)r;
}

// async global->LDS, 16B per lane; LDS dest wave-uniform base (HW adds lane*16).
static __device__ __forceinline__ void stage16(const void* g, void* l) {
    __builtin_amdgcn_global_load_lds(
        (__attribute__((address_space(1))) void*)g,
        (__attribute__((address_space(3))) void*)l, 16, 0, 0);
}

// Pass A: L2-normalize proxies -> bf16 (XOR-swizzled rows); embeddings -> bf16.
// Swizzle: within each 256B row, 16B slot at byte b stored at b ^ ((row&7)<<4).
// Also initializes minneg sentinels, loss accumulator, finalize ticket.
__global__ void prep_kernel(const float* __restrict__ prox,
                            const float* __restrict__ emb,
                            unsigned short* __restrict__ pn,
                            unsigned short* __restrict__ en,
                            unsigned int* __restrict__ minneg,
                            float* __restrict__ accum,
                            unsigned int* __restrict__ ticket,
                            int C, int B) {
    unsigned gtid = blockIdx.x * blockDim.x + threadIdx.x;
    if (gtid < (unsigned)B) minneg[gtid] = 0xFFFFFFFFu;
    if (gtid == 0) { *accum = 0.f; *ticket = 0u; }

    int wave = blockIdx.x * (blockDim.x >> 6) + (threadIdx.x >> 6);
    int lane = threadIdx.x & 63;
    int half = lane >> 5;
    int l32  = lane & 31;
    int row = wave * 2 + half;
    if (row >= C + B) return;

    if (row < C) {
        float4 v = *(const float4*)(prox + (size_t)row * D + l32 * 4);
        float ss = v.x * v.x + v.y * v.y + v.z * v.z + v.w * v.w;
        #pragma unroll
        for (int m = 1; m < 32; m <<= 1) ss += __shfl_xor(ss, m);
        float scale = rsqrtf(ss);
        uint2 pack;
        pack.x = (unsigned)f2bf(v.x * scale) | ((unsigned)f2bf(v.y * scale) << 16);
        pack.y = (unsigned)f2bf(v.z * scale) | ((unsigned)f2bf(v.w * scale) << 16);
        unsigned off = (unsigned)(l32 * 8) ^ (((unsigned)row & 7u) << 4);
        *(uint2*)((char*)(pn + (size_t)row * D) + off) = pack;
    } else {
        int r = row - C;
        float4 v = *(const float4*)(emb + (size_t)r * D + l32 * 4);
        uint2 pack;
        pack.x = (unsigned)f2bf(v.x) | ((unsigned)f2bf(v.y) << 16);
        pack.y = (unsigned)f2bf(v.z) | ((unsigned)f2bf(v.w) << 16);
        *(uint2*)(en + (size_t)r * D + l32 * 4) = pack;
    }
}

// Pass B: fused bf16 GEMM + per-row max over negatives.
// XCD-swizzled 1-D grid (2000 blocks). Block = 4 waves, 256 rows; slab 400 cols.
// B double-buffered in LDS via global_load_lds; fully unrolled 5-phase schedule
// so every ds_read_b128 is base-reg + immediate offset (zero addr VALU).
// launch_bounds (256,3): 3 waves/SIMD -> <=168 VGPR budget, NO spill (r7 lesson:
// (256,4)'s 128-reg cap spilled 217MB of scratch).
__global__ __launch_bounds__(256, 3) void gemmmax_kernel(
        const unsigned short* __restrict__ en,
        const unsigned short* __restrict__ pn,
        const int* __restrict__ labels,
        unsigned int* __restrict__ minneg) {
    __shared__ char smem[2 * CHUNK_BYTES];   // 40 KiB -> 3 blocks/CU (120 KB)

    int n = blockIdx.x;
    int chunkg = gridDim.x >> 3;             // 250 per XCD
    int wgid = (n & 7) * chunkg + (n >> 3);
    int slab   = wgid >> 3;
    int rowgrp = wgid & (ROWG - 1);

    int lane = threadIdx.x & 63;
    int wid  = threadIdx.x >> 6;
    int wbase = rowgrp * 256 + wid * 64;
    int r16 = lane & 15;
    int g   = lane >> 4;
    int col0 = slab * SLAB;
    int swz = (r16 & 7) << 4;

    const char* slabSrc = (const char*)pn + (size_t)col0 * (D * 2);
    int stago = wid * 1024 + lane * 16;

#define STAGE_CHUNK(T, BUF)                                                     \
    {                                                                           \
        const char* gs_ = slabSrc + (size_t)((T) * CHUNK_BYTES) + stago;        \
        char* ls_ = smem + (BUF) * CHUNK_BYTES + wid * 1024;                    \
        stage16(gs_,          ls_);                                             \
        stage16(gs_ + 4096,   ls_ + 4096);                                      \
        stage16(gs_ + 8192,   ls_ + 8192);                                      \
        stage16(gs_ + 12288,  ls_ + 12288);                                     \
        stage16(gs_ + 16384,  ls_ + 16384);                                     \
    }

    STAGE_CHUNK(0, 0)

    // A fragments: lane l, slot j -> E[row = wbase+s4*16+(l&15)][k = k4*32+(l>>4)*8+j]
    bf16x8 a[4][4];
    #pragma unroll
    for (int s4 = 0; s4 < 4; ++s4)
        #pragma unroll
        for (int k4 = 0; k4 < 4; ++k4)
            a[s4][k4] = *(const bf16x8*)(en + (size_t)(wbase + s4 * 16 + r16) * D + k4 * 32 + g * 8);

    // wave-uniform bitmask of steps containing a positive class
    unsigned bits = 0;
    #pragma unroll
    for (int s4 = 0; s4 < 4; ++s4)
        #pragma unroll
        for (int i = 0; i < 4; ++i) {
            int lb = labels[wbase + s4 * 16 + g * 4 + i];
            int pc = lb - col0;
            if (pc >= 0 && pc < SLAB) bits |= 1u << (pc >> 4);
        }
    #pragma unroll
    for (int m = 1; m < 64; m <<= 1) bits |= __shfl_xor(bits, m);
    unsigned sbits = __builtin_amdgcn_readfirstlane(bits);

    float rm[4][4];
    #pragma unroll
    for (int s4 = 0; s4 < 4; ++s4)
        #pragma unroll
        for (int i = 0; i < 4; ++i) rm[s4][i] = -1e30f;

    const f32x4 zero = {0.f, 0.f, 0.f, 0.f};
    // per-lane LDS base pointers; all step/buffer offsets are immediates
    const char* p0 = smem + r16 * 256 + ((g * 16 + 0)   ^ swz);
    const char* p1 = smem + r16 * 256 + ((g * 16 + 64)  ^ swz);
    const char* p2 = smem + r16 * 256 + ((g * 16 + 128) ^ swz);
    const char* p3 = smem + r16 * 256 + ((g * 16 + 192) ^ swz);

#define MFMA __builtin_amdgcn_mfma_f32_16x16x32_bf16
#define DO_STEP(BASE, STEP)                                                     \
    {                                                                           \
        bf16x8 b0 = *(const bf16x8*)(p0 + (BASE));                              \
        bf16x8 b1 = *(const bf16x8*)(p1 + (BASE));                              \
        bf16x8 b2 = *(const bf16x8*)(p2 + (BASE));                              \
        bf16x8 b3 = *(const bf16x8*)(p3 + (BASE));                              \
        f32x4 cc[4];                                                            \
        _Pragma("unroll")                                                       \
        for (int s4 = 0; s4 < 4; ++s4) cc[s4] = MFMA(a[s4][0], b0, zero, 0, 0, 0); \
        _Pragma("unroll")                                                       \
        for (int s4 = 0; s4 < 4; ++s4) cc[s4] = MFMA(a[s4][1], b1, cc[s4], 0, 0, 0); \
        _Pragma("unroll")                                                       \
        for (int s4 = 0; s4 < 4; ++s4) cc[s4] = MFMA(a[s4][2], b2, cc[s4], 0, 0, 0); \
        _Pragma("unroll")                                                       \
        for (int s4 = 0; s4 < 4; ++s4) cc[s4] = MFMA(a[s4][3], b3, cc[s4], 0, 0, 0); \
        if (__builtin_expect((sbits >> (STEP)) & 1u, 0)) {                      \
            int colg = col0 + (STEP) * 16 + r16;                                \
            _Pragma("unroll")                                                   \
            for (int s4 = 0; s4 < 4; ++s4)                                      \
                _Pragma("unroll")                                               \
                for (int i = 0; i < 4; ++i) {                                   \
                    int lb2 = labels[wbase + s4 * 16 + g * 4 + i];              \
                    float v = (colg == lb2) ? -1e30f : cc[s4][i];               \
                    rm[s4][i] = fmaxf(rm[s4][i], v);                            \
                }                                                               \
        } else {                                                                \
            _Pragma("unroll")                                                   \
            for (int s4 = 0; s4 < 4; ++s4)                                      \
                _Pragma("unroll")                                               \
                for (int i = 0; i < 4; ++i)                                     \
                    rm[s4][i] = fmaxf(rm[s4][i], cc[s4][i]);                    \
        }                                                                       \
    }

#define STEPS5(BASE, T0)                                                        \
    DO_STEP((BASE) + 0,     (T0) + 0)                                           \
    DO_STEP((BASE) + 4096,  (T0) + 1)                                           \
    DO_STEP((BASE) + 8192,  (T0) + 2)                                           \
    DO_STEP((BASE) + 12288, (T0) + 3)                                           \
    DO_STEP((BASE) + 16384, (T0) + 4)

    __syncthreads();                       // chunk 0 resident
    STAGE_CHUNK(1, 1) STEPS5(0, 0)              __syncthreads();
    STAGE_CHUNK(2, 0) STEPS5(CHUNK_BYTES, 5)    __syncthreads();
    STAGE_CHUNK(3, 1) STEPS5(0, 10)             __syncthreads();
    STAGE_CHUNK(4, 0) STEPS5(CHUNK_BYTES, 15)   __syncthreads();
    STEPS5(0, 20)
#undef STEPS5
#undef DO_STEP
#undef MFMA
#undef STAGE_CHUNK

    // reduce max across the 16 lanes of each row-group, combine across blocks
    #pragma unroll
    for (int s4 = 0; s4 < 4; ++s4)
        #pragma unroll
        for (int i = 0; i < 4; ++i) {
            float v = rm[s4][i];
            v = fmaxf(v, __shfl_xor(v, 1));
            v = fmaxf(v, __shfl_xor(v, 2));
            v = fmaxf(v, __shfl_xor(v, 4));
            v = fmaxf(v, __shfl_xor(v, 8));
            if (r16 == 0) {
                int r = wbase + s4 * 16 + g * 4 + i;
                float md = fmaxf(2.f - 2.f * v, 0.f);  // >=0 -> uint order == float order
                atomicMin(minneg + r, __float_as_uint(md));
            }
        }
}

// Pass C: exact fp32 positive distance + per-row loss; last block writes the mean.
__global__ void finalize_kernel(const float* __restrict__ emb,
                                const float* __restrict__ prox,
                                const int* __restrict__ labels,
                                const unsigned int* __restrict__ minneg,
                                float* __restrict__ accum,
                                unsigned int* __restrict__ ticket,
                                float* __restrict__ out, int B) {
    int wave = blockIdx.x * (blockDim.x >> 6) + (threadIdx.x >> 6);
    int lane = threadIdx.x & 63;
    if (wave < B) {
        int lab = labels[wave];
        float2 e = *(const float2*)(emb + (size_t)wave * D + lane * 2);
        float2 p = *(const float2*)(prox + (size_t)lab * D + lane * 2);
        float spp = p.x * p.x + p.y * p.y;
        float sep = e.x * p.x + e.y * p.y;
        #pragma unroll
        for (int m = 1; m < 64; m <<= 1) {
            spp += __shfl_xor(spp, m);
            sep += __shfl_xor(sep, m);
        }
        if (lane == 0) {
            float pos_sim = sep * rsqrtf(spp);
            float pos_dist = 2.f - 2.f * pos_sim;
            float mn = __uint_as_float(minneg[wave]);
            float loss = fmaxf(pos_dist + LOSS_MARGIN - mn, 0.f);
            atomicAdd(accum, loss);
        }
    }
    __threadfence();
    __syncthreads();
    if (threadIdx.x == 0) {
        unsigned old = atomicAdd(ticket, 1u);
        if (old == gridDim.x - 1) {            // last block: all adds visible
            __threadfence();
            float total = atomicAdd(accum, 0.f);   // coherent read
            out[0] = total * (1.f / (float)B);
        }
    }
}

extern "C" void kernel_launch(void* const* d_in, const int* in_sizes, int n_in,
                              void* d_out, int out_size, void* d_ws, size_t ws_size,
                              hipStream_t stream) {
    const float* emb  = (const float*)d_in[0];
    const float* prox = (const float*)d_in[1];
    const int*   labels = (const int*)d_in[2];
    int B = in_sizes[0] / D;  // 2048
    int C = in_sizes[1] / D;  // 100000

    char* ws = (char*)d_ws;
    unsigned short* pn = (unsigned short*)ws;                       // C*D bf16 (swizzled rows)
    size_t offEN  = (size_t)C * D * 2 + (size_t)64 * D * 2;
    unsigned short* en = (unsigned short*)(ws + offEN);             // B*D bf16
    size_t offMIN = offEN + (size_t)B * D * 2;
    unsigned int* minneg = (unsigned int*)(ws + offMIN);            // B u32
    size_t offACC = offMIN + (size_t)B * 4;
    float* accum = (float*)(ws + offACC);                           // 1 f32
    unsigned int* ticket = (unsigned int*)(ws + offACC + 64);       // 1 u32

    int totalRows = C + B;
    int prepWaves = (totalRows + 1) / 2;
    prep_kernel<<<dim3((prepWaves + 3) / 4), dim3(256), 0, stream>>>(
        prox, emb, pn, en, minneg, accum, ticket, C, B);
    gemmmax_kernel<<<dim3((B / 256) * (C / SLAB)), dim3(256), 0, stream>>>(
        en, pn, labels, minneg);
    finalize_kernel<<<dim3((B + 3) / 4), dim3(256), 0, stream>>>(
        emb, prox, labels, minneg, accum, ticket, (float*)d_out, B);
}

// Round 10
// 201.179 us; speedup vs baseline: 1.2463x; 1.0104x over previous
//
#include <hip/hip_runtime.h>
#include <hip/hip_bf16.h>

#define D 128
#define LOSS_MARGIN 0.2f
#define SPB 25                 // 16-col MFMA steps per block
#define SLAB (SPB * 16)        // 400 cols; C = 250 slabs * 400
#define ROWG 8                 // 2048 / 256 row-groups
#define CHUNK_BYTES 20480      // 80 cols * 256 B

typedef __attribute__((ext_vector_type(8))) short bf16x8;
typedef __attribute__((ext_vector_type(4))) float f32x4;

static __device__ __forceinline__ unsigned short f2bf(float f) {
    unsigned u = __float_as_uint(f);
    unsigned r = (u + 0x7FFFu + ((u >> 16) & 1u)) >> 16;  // RNE
    return (unsigned short)r;
}

// async global->LDS, 16B per lane; LDS dest wave-uniform base (HW adds lane*16).
static __device__ __forceinline__ void stage16(const void* g, void* l) {
    __builtin_amdgcn_global_load_lds(
        (__attribute__((address_space(1))) void*)g,
        (__attribute__((address_space(3))) void*)l, 16, 0, 0);
}

// Pass A: L2-normalize proxies -> bf16 (XOR-swizzled rows); embeddings -> bf16.
// Swizzle: within each 256B row, 16B slot p stored at p ^ (row & 15)  [full
// 4-bit key: r9 counters proved the 3-bit key left a 2-way ds_read conflict].
// Also initializes minneg sentinels, loss accumulator, finalize ticket.
__global__ void prep_kernel(const float* __restrict__ prox,
                            const float* __restrict__ emb,
                            unsigned short* __restrict__ pn,
                            unsigned short* __restrict__ en,
                            unsigned int* __restrict__ minneg,
                            float* __restrict__ accum,
                            unsigned int* __restrict__ ticket,
                            int C, int B) {
    unsigned gtid = blockIdx.x * blockDim.x + threadIdx.x;
    if (gtid < (unsigned)B) minneg[gtid] = 0xFFFFFFFFu;
    if (gtid == 0) { *accum = 0.f; *ticket = 0u; }

    int wave = blockIdx.x * (blockDim.x >> 6) + (threadIdx.x >> 6);
    int lane = threadIdx.x & 63;
    int half = lane >> 5;
    int l32  = lane & 31;
    int row = wave * 2 + half;
    if (row >= C + B) return;

    if (row < C) {
        float4 v = *(const float4*)(prox + (size_t)row * D + l32 * 4);
        float ss = v.x * v.x + v.y * v.y + v.z * v.z + v.w * v.w;
        #pragma unroll
        for (int m = 1; m < 32; m <<= 1) ss += __shfl_xor(ss, m);
        float scale = rsqrtf(ss);
        uint2 pack;
        pack.x = (unsigned)f2bf(v.x * scale) | ((unsigned)f2bf(v.y * scale) << 16);
        pack.y = (unsigned)f2bf(v.z * scale) | ((unsigned)f2bf(v.w * scale) << 16);
        unsigned off = (unsigned)(l32 * 8) ^ (((unsigned)row & 15u) << 4);
        *(uint2*)((char*)(pn + (size_t)row * D) + off) = pack;
    } else {
        int r = row - C;
        float4 v = *(const float4*)(emb + (size_t)r * D + l32 * 4);
        uint2 pack;
        pack.x = (unsigned)f2bf(v.x) | ((unsigned)f2bf(v.y) << 16);
        pack.y = (unsigned)f2bf(v.z) | ((unsigned)f2bf(v.w) << 16);
        *(uint2*)(en + (size_t)r * D + l32 * 4) = pack;
    }
}

// Pass B: fused bf16 GEMM + per-row max over negatives.
// XCD-swizzled 1-D grid (2000 blocks). Block = 4 waves, 256 rows; slab 400 cols.
// B double-buffered in LDS via global_load_lds; fully unrolled 5-phase schedule
// so every ds_read_b128 is base-reg + immediate offset.
// launch_bounds (256,2): this structure needs ~200 VGPR; (256,3)=168 budget
// spilled 86MB scratch (r9), (256,4)=128 spilled 217MB (r7). 2 is spill-free.
__global__ __launch_bounds__(256, 2) void gemmmax_kernel(
        const unsigned short* __restrict__ en,
        const unsigned short* __restrict__ pn,
        const int* __restrict__ labels,
        unsigned int* __restrict__ minneg) {
    __shared__ char smem[2 * CHUNK_BYTES];   // 40 KiB

    int n = blockIdx.x;
    int chunkg = gridDim.x >> 3;             // 250 per XCD
    int wgid = (n & 7) * chunkg + (n >> 3);
    int slab   = wgid >> 3;
    int rowgrp = wgid & (ROWG - 1);

    int lane = threadIdx.x & 63;
    int wid  = threadIdx.x >> 6;
    int wbase = rowgrp * 256 + wid * 64;
    int r16 = lane & 15;
    int g   = lane >> 4;
    int col0 = slab * SLAB;
    int swz = r16 << 4;                      // full 4-bit key: conflict-free b128

    const char* slabSrc = (const char*)pn + (size_t)col0 * (D * 2);
    int stago = wid * 1024 + lane * 16;

#define STAGE_CHUNK(T, BUF)                                                     \
    {                                                                           \
        const char* gs_ = slabSrc + (size_t)((T) * CHUNK_BYTES) + stago;        \
        char* ls_ = smem + (BUF) * CHUNK_BYTES + wid * 1024;                    \
        stage16(gs_,          ls_);                                             \
        stage16(gs_ + 4096,   ls_ + 4096);                                      \
        stage16(gs_ + 8192,   ls_ + 8192);                                      \
        stage16(gs_ + 12288,  ls_ + 12288);                                     \
        stage16(gs_ + 16384,  ls_ + 16384);                                     \
    }

    STAGE_CHUNK(0, 0)

    // A fragments: lane l, slot j -> E[row = wbase+s4*16+(l&15)][k = k4*32+(l>>4)*8+j]
    bf16x8 a[4][4];
    #pragma unroll
    for (int s4 = 0; s4 < 4; ++s4)
        #pragma unroll
        for (int k4 = 0; k4 < 4; ++k4)
            a[s4][k4] = *(const bf16x8*)(en + (size_t)(wbase + s4 * 16 + r16) * D + k4 * 32 + g * 8);

    // wave-uniform bitmask of steps containing a positive class
    unsigned bits = 0;
    #pragma unroll
    for (int s4 = 0; s4 < 4; ++s4)
        #pragma unroll
        for (int i = 0; i < 4; ++i) {
            int lb = labels[wbase + s4 * 16 + g * 4 + i];
            int pc = lb - col0;
            if (pc >= 0 && pc < SLAB) bits |= 1u << (pc >> 4);
        }
    #pragma unroll
    for (int m = 1; m < 64; m <<= 1) bits |= __shfl_xor(bits, m);
    unsigned sbits = __builtin_amdgcn_readfirstlane(bits);

    float rm[4][4];
    #pragma unroll
    for (int s4 = 0; s4 < 4; ++s4)
        #pragma unroll
        for (int i = 0; i < 4; ++i) rm[s4][i] = -1e30f;

    const f32x4 zero = {0.f, 0.f, 0.f, 0.f};
    // per-lane LDS base pointers; all step/buffer offsets are immediates.
    // logical 16B slot of read j is (g + 4j); stored slot = (g+4j) ^ r16.
    const char* p0 = smem + r16 * 256 + ((g * 16 + 0)   ^ swz);
    const char* p1 = smem + r16 * 256 + ((g * 16 + 64)  ^ swz);
    const char* p2 = smem + r16 * 256 + ((g * 16 + 128) ^ swz);
    const char* p3 = smem + r16 * 256 + ((g * 16 + 192) ^ swz);

#define MFMA __builtin_amdgcn_mfma_f32_16x16x32_bf16
#define DO_STEP(BASE, STEP)                                                     \
    {                                                                           \
        bf16x8 b0 = *(const bf16x8*)(p0 + (BASE));                              \
        bf16x8 b1 = *(const bf16x8*)(p1 + (BASE));                              \
        bf16x8 b2 = *(const bf16x8*)(p2 + (BASE));                              \
        bf16x8 b3 = *(const bf16x8*)(p3 + (BASE));                              \
        f32x4 cc[4];                                                            \
        _Pragma("unroll")                                                       \
        for (int s4 = 0; s4 < 4; ++s4) cc[s4] = MFMA(a[s4][0], b0, zero, 0, 0, 0); \
        _Pragma("unroll")                                                       \
        for (int s4 = 0; s4 < 4; ++s4) cc[s4] = MFMA(a[s4][1], b1, cc[s4], 0, 0, 0); \
        _Pragma("unroll")                                                       \
        for (int s4 = 0; s4 < 4; ++s4) cc[s4] = MFMA(a[s4][2], b2, cc[s4], 0, 0, 0); \
        _Pragma("unroll")                                                       \
        for (int s4 = 0; s4 < 4; ++s4) cc[s4] = MFMA(a[s4][3], b3, cc[s4], 0, 0, 0); \
        if (__builtin_expect((sbits >> (STEP)) & 1u, 0)) {                      \
            int colg = col0 + (STEP) * 16 + r16;                                \
            _Pragma("unroll")                                                   \
            for (int s4 = 0; s4 < 4; ++s4)                                      \
                _Pragma("unroll")                                               \
                for (int i = 0; i < 4; ++i) {                                   \
                    int lb2 = labels[wbase + s4 * 16 + g * 4 + i];              \
                    float v = (colg == lb2) ? -1e30f : cc[s4][i];               \
                    rm[s4][i] = fmaxf(rm[s4][i], v);                            \
                }                                                               \
        } else {                                                                \
            _Pragma("unroll")                                                   \
            for (int s4 = 0; s4 < 4; ++s4)                                      \
                _Pragma("unroll")                                               \
                for (int i = 0; i < 4; ++i)                                     \
                    rm[s4][i] = fmaxf(rm[s4][i], cc[s4][i]);                    \
        }                                                                       \
    }

#define STEPS5(BASE, T0)                                                        \
    DO_STEP((BASE) + 0,     (T0) + 0)                                           \
    DO_STEP((BASE) + 4096,  (T0) + 1)                                           \
    DO_STEP((BASE) + 8192,  (T0) + 2)                                           \
    DO_STEP((BASE) + 12288, (T0) + 3)                                           \
    DO_STEP((BASE) + 16384, (T0) + 4)

    __syncthreads();                       // chunk 0 resident
    STAGE_CHUNK(1, 1) STEPS5(0, 0)              __syncthreads();
    STAGE_CHUNK(2, 0) STEPS5(CHUNK_BYTES, 5)    __syncthreads();
    STAGE_CHUNK(3, 1) STEPS5(0, 10)             __syncthreads();
    STAGE_CHUNK(4, 0) STEPS5(CHUNK_BYTES, 15)   __syncthreads();
    STEPS5(0, 20)
#undef STEPS5
#undef DO_STEP
#undef MFMA
#undef STAGE_CHUNK

    // reduce max across the 16 lanes of each row-group, combine across blocks
    #pragma unroll
    for (int s4 = 0; s4 < 4; ++s4)
        #pragma unroll
        for (int i = 0; i < 4; ++i) {
            float v = rm[s4][i];
            v = fmaxf(v, __shfl_xor(v, 1));
            v = fmaxf(v, __shfl_xor(v, 2));
            v = fmaxf(v, __shfl_xor(v, 4));
            v = fmaxf(v, __shfl_xor(v, 8));
            if (r16 == 0) {
                int r = wbase + s4 * 16 + g * 4 + i;
                float md = fmaxf(2.f - 2.f * v, 0.f);  // >=0 -> uint order == float order
                atomicMin(minneg + r, __float_as_uint(md));
            }
        }
}

// Pass C: exact fp32 positive distance + per-row loss; last block writes the mean.
__global__ void finalize_kernel(const float* __restrict__ emb,
                                const float* __restrict__ prox,
                                const int* __restrict__ labels,
                                const unsigned int* __restrict__ minneg,
                                float* __restrict__ accum,
                                unsigned int* __restrict__ ticket,
                                float* __restrict__ out, int B) {
    int wave = blockIdx.x * (blockDim.x >> 6) + (threadIdx.x >> 6);
    int lane = threadIdx.x & 63;
    if (wave < B) {
        int lab = labels[wave];
        float2 e = *(const float2*)(emb + (size_t)wave * D + lane * 2);
        float2 p = *(const float2*)(prox + (size_t)lab * D + lane * 2);
        float spp = p.x * p.x + p.y * p.y;
        float sep = e.x * p.x + e.y * p.y;
        #pragma unroll
        for (int m = 1; m < 64; m <<= 1) {
            spp += __shfl_xor(spp, m);
            sep += __shfl_xor(sep, m);
        }
        if (lane == 0) {
            float pos_sim = sep * rsqrtf(spp);
            float pos_dist = 2.f - 2.f * pos_sim;
            float mn = __uint_as_float(minneg[wave]);
            float loss = fmaxf(pos_dist + LOSS_MARGIN - mn, 0.f);
            atomicAdd(accum, loss);
        }
    }
    __threadfence();
    __syncthreads();
    if (threadIdx.x == 0) {
        unsigned old = atomicAdd(ticket, 1u);
        if (old == gridDim.x - 1) {            // last block: all adds visible
            __threadfence();
            float total = atomicAdd(accum, 0.f);   // coherent read
            out[0] = total * (1.f / (float)B);
        }
    }
}

extern "C" void kernel_launch(void* const* d_in, const int* in_sizes, int n_in,
                              void* d_out, int out_size, void* d_ws, size_t ws_size,
                              hipStream_t stream) {
    const float* emb  = (const float*)d_in[0];
    const float* prox = (const float*)d_in[1];
    const int*   labels = (const int*)d_in[2];
    int B = in_sizes[0] / D;  // 2048
    int C = in_sizes[1] / D;  // 100000

    char* ws = (char*)d_ws;
    unsigned short* pn = (unsigned short*)ws;                       // C*D bf16 (swizzled rows)
    size_t offEN  = (size_t)C * D * 2 + (size_t)64 * D * 2;
    unsigned short* en = (unsigned short*)(ws + offEN);             // B*D bf16
    size_t offMIN = offEN + (size_t)B * D * 2;
    unsigned int* minneg = (unsigned int*)(ws + offMIN);            // B u32
    size_t offACC = offMIN + (size_t)B * 4;
    float* accum = (float*)(ws + offACC);                           // 1 f32
    unsigned int* ticket = (unsigned int*)(ws + offACC + 64);       // 1 u32

    int totalRows = C + B;
    int prepWaves = (totalRows + 1) / 2;
    prep_kernel<<<dim3((prepWaves + 3) / 4), dim3(256), 0, stream>>>(
        prox, emb, pn, en, minneg, accum, ticket, C, B);
    gemmmax_kernel<<<dim3((B / 256) * (C / SLAB)), dim3(256), 0, stream>>>(
        en, pn, labels, minneg);
    finalize_kernel<<<dim3((B + 3) / 4), dim3(256), 0, stream>>>(
        emb, prox, labels, minneg, accum, ticket, (float*)d_out, B);
}

// Round 13
// 198.110 us; speedup vs baseline: 1.2656x; 1.0155x over previous
//
#include <hip/hip_runtime.h>
#include <hip/hip_bf16.h>

#define D 128
#define LOSS_MARGIN 0.2f
#define SPB 25                 // 16-col MFMA steps per block
#define SLAB (SPB * 16)        // 400 cols; C = 250 slabs * 400
#define ROWG 8                 // 2048 / 256 row-groups
#define CHUNK_BYTES 20480      // 80 cols * 256 B

typedef __attribute__((ext_vector_type(8))) short bf16x8;
typedef __attribute__((ext_vector_type(4))) float f32x4;

static __device__ __forceinline__ unsigned short f2bf(float f) {
    unsigned u = __float_as_uint(f);
    unsigned r = (u + 0x7FFFu + ((u >> 16) & 1u)) >> 16;  // RNE
    return (unsigned short)r;
}

// async global->LDS, 16B per lane; LDS dest wave-uniform base (HW adds lane*16).
static __device__ __forceinline__ void stage16(const void* g, void* l) {
    __builtin_amdgcn_global_load_lds(
        (__attribute__((address_space(1))) void*)g,
        (__attribute__((address_space(3))) void*)l, 16, 0, 0);
}

// Pass A: L2-normalize proxies -> bf16 ; embeddings -> bf16. LINEAR layout,
// 16B/lane loads and stores (r10 post-mortem: swizzled 8B scattered stores were
// the prep suspect; swizzle now lives on the gemm STAGE source address).
// 4 rows per wave (16 lanes/row). Also inits minneg/accum/ticket.
__global__ void prep_kernel(const float* __restrict__ prox,
                            const float* __restrict__ emb,
                            unsigned short* __restrict__ pn,
                            unsigned short* __restrict__ en,
                            unsigned int* __restrict__ minneg,
                            float* __restrict__ accum,
                            unsigned int* __restrict__ ticket,
                            int C, int B) {
    unsigned gtid = blockIdx.x * blockDim.x + threadIdx.x;
    if (gtid < (unsigned)B) minneg[gtid] = 0xFFFFFFFFu;
    if (gtid == 0) { *accum = 0.f; *ticket = 0u; }

    int wave = blockIdx.x * (blockDim.x >> 6) + (threadIdx.x >> 6);
    int lane = threadIdx.x & 63;
    int sub = lane >> 4;       // which of the wave's 4 rows
    int l16 = lane & 15;
    int row = wave * 4 + sub;
    if (row >= C + B) return;

    const float* src;
    unsigned short* dst;
    bool donorm;
    if (row < C) { src = prox + (size_t)row * D; dst = pn + (size_t)row * D; donorm = true; }
    else { int r = row - C; src = emb + (size_t)r * D; dst = en + (size_t)r * D; donorm = false; }

    float4 v0 = *(const float4*)(src + l16 * 8);
    float4 v1 = *(const float4*)(src + l16 * 8 + 4);
    float scale = 1.f;
    if (donorm) {  // 16-lane-group reduction (xor masks < 16 stay in-group)
        float ss = v0.x * v0.x + v0.y * v0.y + v0.z * v0.z + v0.w * v0.w
                 + v1.x * v1.x + v1.y * v1.y + v1.z * v1.z + v1.w * v1.w;
        #pragma unroll
        for (int m = 1; m < 16; m <<= 1) ss += __shfl_xor(ss, m);
        scale = rsqrtf(ss);
    }
    uint4 pack;
    pack.x = (unsigned)f2bf(v0.x * scale) | ((unsigned)f2bf(v0.y * scale) << 16);
    pack.y = (unsigned)f2bf(v0.z * scale) | ((unsigned)f2bf(v0.w * scale) << 16);
    pack.z = (unsigned)f2bf(v1.x * scale) | ((unsigned)f2bf(v1.y * scale) << 16);
    pack.w = (unsigned)f2bf(v1.z * scale) | ((unsigned)f2bf(v1.w * scale) << 16);
    *(uint4*)(dst + l16 * 8) = pack;
}

// Pass B: fused bf16 GEMM + per-row max over negatives.
// XCD-swizzled 1-D grid (2000 blocks). Block = 4 waves, 256 rows; slab 400 cols.
// B staged via global_load_lds with PRE-SWIZZLED SOURCE address (linear global,
// linear LDS dest, XOR-swizzled ds_read — m173/rule-21 pattern).
// launch_bounds (256,2): structure needs ~200 VGPR; 3 and 4 waves/SIMD spilled.
__global__ __launch_bounds__(256, 2) void gemmmax_kernel(
        const unsigned short* __restrict__ en,
        const unsigned short* __restrict__ pn,
        const int* __restrict__ labels,
        unsigned int* __restrict__ minneg) {
    __shared__ char smem[2 * CHUNK_BYTES];   // 40 KiB

    int n = blockIdx.x;
    int chunkg = gridDim.x >> 3;             // 250 per XCD
    int wgid = (n & 7) * chunkg + (n >> 3);
    int slab   = wgid >> 3;
    int rowgrp = wgid & (ROWG - 1);

    int lane = threadIdx.x & 63;
    int wid  = threadIdx.x >> 6;
    int wbase = rowgrp * 256 + wid * 64;
    int r16 = lane & 15;
    int g   = lane >> 4;
    int col0 = slab * SLAB;
    int swz = r16 << 4;                      // 4-bit key: conflict-free b128 (r10: 0 conflicts)

    const char* slabSrc = (const char*)pn + (size_t)col0 * (D * 2);
    int stago = wid * 1024 + lane * 16;
    // source-side swizzle: LDS byte o receives global byte with 16B-slot
    // (o>>4)&15 XOR'd by row-in-chunk (o>>8)&15. Invariant under +r*4096 and
    // +t*CHUNK (only bits >=12 change; (row&15) unchanged since 80,400 == 0 mod 16).
    int srcswz = (stago & ~0xF0) | (((((stago >> 4) & 15) ^ ((stago >> 8) & 15))) << 4);

#define STAGE_CHUNK(T, BUF)                                                     \
    {                                                                           \
        const char* gs_ = slabSrc + (size_t)((T) * CHUNK_BYTES) + srcswz;       \
        char* ls_ = smem + (BUF) * CHUNK_BYTES + wid * 1024;                    \
        stage16(gs_,          ls_);                                             \
        stage16(gs_ + 4096,   ls_ + 4096);                                      \
        stage16(gs_ + 8192,   ls_ + 8192);                                      \
        stage16(gs_ + 12288,  ls_ + 12288);                                     \
        stage16(gs_ + 16384,  ls_ + 16384);                                     \
    }

    STAGE_CHUNK(0, 0)

    // A fragments: lane l, slot j -> E[row = wbase+s4*16+(l&15)][k = k4*32+(l>>4)*8+j]
    bf16x8 a[4][4];
    #pragma unroll
    for (int s4 = 0; s4 < 4; ++s4)
        #pragma unroll
        for (int k4 = 0; k4 < 4; ++k4)
            a[s4][k4] = *(const bf16x8*)(en + (size_t)(wbase + s4 * 16 + r16) * D + k4 * 32 + g * 8);

    // wave-uniform bitmask of steps containing a positive class
    unsigned bits = 0;
    #pragma unroll
    for (int s4 = 0; s4 < 4; ++s4)
        #pragma unroll
        for (int i = 0; i < 4; ++i) {
            int lb = labels[wbase + s4 * 16 + g * 4 + i];
            int pc = lb - col0;
            if (pc >= 0 && pc < SLAB) bits |= 1u << (pc >> 4);
        }
    #pragma unroll
    for (int m = 1; m < 64; m <<= 1) bits |= __shfl_xor(bits, m);
    unsigned sbits = __builtin_amdgcn_readfirstlane(bits);

    float rm[4][4];
    #pragma unroll
    for (int s4 = 0; s4 < 4; ++s4)
        #pragma unroll
        for (int i = 0; i < 4; ++i) rm[s4][i] = -1e30f;

    const f32x4 zero = {0.f, 0.f, 0.f, 0.f};
    // per-lane LDS base pointers; all step/buffer offsets are immediates.
    // logical 16B slot of read j is (g + 4j); stored slot = (g+4j) ^ r16.
    const char* p0 = smem + r16 * 256 + ((g * 16 + 0)   ^ swz);
    const char* p1 = smem + r16 * 256 + ((g * 16 + 64)  ^ swz);
    const char* p2 = smem + r16 * 256 + ((g * 16 + 128) ^ swz);
    const char* p3 = smem + r16 * 256 + ((g * 16 + 192) ^ swz);

#define MFMA __builtin_amdgcn_mfma_f32_16x16x32_bf16
#define DO_STEP(BASE, STEP)                                                     \
    {                                                                           \
        bf16x8 b0 = *(const bf16x8*)(p0 + (BASE));                              \
        bf16x8 b1 = *(const bf16x8*)(p1 + (BASE));                              \
        bf16x8 b2 = *(const bf16x8*)(p2 + (BASE));                              \
        bf16x8 b3 = *(const bf16x8*)(p3 + (BASE));                              \
        f32x4 cc[4];                                                            \
        _Pragma("unroll")                                                       \
        for (int s4 = 0; s4 < 4; ++s4) cc[s4] = MFMA(a[s4][0], b0, zero, 0, 0, 0); \
        _Pragma("unroll")                                                       \
        for (int s4 = 0; s4 < 4; ++s4) cc[s4] = MFMA(a[s4][1], b1, cc[s4], 0, 0, 0); \
        _Pragma("unroll")                                                       \
        for (int s4 = 0; s4 < 4; ++s4) cc[s4] = MFMA(a[s4][2], b2, cc[s4], 0, 0, 0); \
        _Pragma("unroll")                                                       \
        for (int s4 = 0; s4 < 4; ++s4) cc[s4] = MFMA(a[s4][3], b3, cc[s4], 0, 0, 0); \
        if (__builtin_expect((sbits >> (STEP)) & 1u, 0)) {                      \
            int colg = col0 + (STEP) * 16 + r16;                                \
            _Pragma("unroll")                                                   \
            for (int s4 = 0; s4 < 4; ++s4)                                      \
                _Pragma("unroll")                                               \
                for (int i = 0; i < 4; ++i) {                                   \
                    int lb2 = labels[wbase + s4 * 16 + g * 4 + i];              \
                    float v = (colg == lb2) ? -1e30f : cc[s4][i];               \
                    rm[s4][i] = fmaxf(rm[s4][i], v);                            \
                }                                                               \
        } else {                                                                \
            _Pragma("unroll")                                                   \
            for (int s4 = 0; s4 < 4; ++s4)                                      \
                _Pragma("unroll")                                               \
                for (int i = 0; i < 4; ++i)                                     \
                    rm[s4][i] = fmaxf(rm[s4][i], cc[s4][i]);                    \
        }                                                                       \
    }

#define STEPS5(BASE, T0)                                                        \
    DO_STEP((BASE) + 0,     (T0) + 0)                                           \
    DO_STEP((BASE) + 4096,  (T0) + 1)                                           \
    DO_STEP((BASE) + 8192,  (T0) + 2)                                           \
    DO_STEP((BASE) + 12288, (T0) + 3)                                           \
    DO_STEP((BASE) + 16384, (T0) + 4)

    __syncthreads();                       // chunk 0 resident
    STAGE_CHUNK(1, 1) STEPS5(0, 0)              __syncthreads();
    STAGE_CHUNK(2, 0) STEPS5(CHUNK_BYTES, 5)    __syncthreads();
    STAGE_CHUNK(3, 1) STEPS5(0, 10)             __syncthreads();
    STAGE_CHUNK(4, 0) STEPS5(CHUNK_BYTES, 15)   __syncthreads();
    STEPS5(0, 20)
#undef STEPS5
#undef DO_STEP
#undef MFMA
#undef STAGE_CHUNK

    // reduce max across the 16 lanes of each row-group, combine across blocks
    #pragma unroll
    for (int s4 = 0; s4 < 4; ++s4)
        #pragma unroll
        for (int i = 0; i < 4; ++i) {
            float v = rm[s4][i];
            v = fmaxf(v, __shfl_xor(v, 1));
            v = fmaxf(v, __shfl_xor(v, 2));
            v = fmaxf(v, __shfl_xor(v, 4));
            v = fmaxf(v, __shfl_xor(v, 8));
            if (r16 == 0) {
                int r = wbase + s4 * 16 + g * 4 + i;
                float md = fmaxf(2.f - 2.f * v, 0.f);  // >=0 -> uint order == float order
                atomicMin(minneg + r, __float_as_uint(md));
            }
        }
}

// Pass C: exact fp32 positive distance + per-row loss; last block writes the mean.
__global__ void finalize_kernel(const float* __restrict__ emb,
                                const float* __restrict__ prox,
                                const int* __restrict__ labels,
                                const unsigned int* __restrict__ minneg,
                                float* __restrict__ accum,
                                unsigned int* __restrict__ ticket,
                                float* __restrict__ out, int B) {
    int wave = blockIdx.x * (blockDim.x >> 6) + (threadIdx.x >> 6);
    int lane = threadIdx.x & 63;
    if (wave < B) {
        int lab = labels[wave];
        float2 e = *(const float2*)(emb + (size_t)wave * D + lane * 2);
        float2 p = *(const float2*)(prox + (size_t)lab * D + lane * 2);
        float spp = p.x * p.x + p.y * p.y;
        float sep = e.x * p.x + e.y * p.y;
        #pragma unroll
        for (int m = 1; m < 64; m <<= 1) {
            spp += __shfl_xor(spp, m);
            sep += __shfl_xor(sep, m);
        }
        if (lane == 0) {
            float pos_sim = sep * rsqrtf(spp);
            float pos_dist = 2.f - 2.f * pos_sim;
            float mn = __uint_as_float(minneg[wave]);
            float loss = fmaxf(pos_dist + LOSS_MARGIN - mn, 0.f);
            atomicAdd(accum, loss);
        }
    }
    __threadfence();
    __syncthreads();
    if (threadIdx.x == 0) {
        unsigned old = atomicAdd(ticket, 1u);
        if (old == gridDim.x - 1) {            // last block: all adds visible
            __threadfence();
            float total = atomicAdd(accum, 0.f);   // coherent read
            out[0] = total * (1.f / (float)B);
        }
    }
}

extern "C" void kernel_launch(void* const* d_in, const int* in_sizes, int n_in,
                              void* d_out, int out_size, void* d_ws, size_t ws_size,
                              hipStream_t stream) {
    const float* emb  = (const float*)d_in[0];
    const float* prox = (const float*)d_in[1];
    const int*   labels = (const int*)d_in[2];
    int B = in_sizes[0] / D;  // 2048
    int C = in_sizes[1] / D;  // 100000

    char* ws = (char*)d_ws;
    unsigned short* pn = (unsigned short*)ws;                       // C*D bf16 (LINEAR)
    size_t offEN  = (size_t)C * D * 2 + (size_t)64 * D * 2;
    unsigned short* en = (unsigned short*)(ws + offEN);             // B*D bf16
    size_t offMIN = offEN + (size_t)B * D * 2;
    unsigned int* minneg = (unsigned int*)(ws + offMIN);            // B u32
    size_t offACC = offMIN + (size_t)B * 4;
    float* accum = (float*)(ws + offACC);                           // 1 f32
    unsigned int* ticket = (unsigned int*)(ws + offACC + 64);       // 1 u32

    int totalRows = C + B;
    int prepWaves = (totalRows + 3) / 4;
    prep_kernel<<<dim3((prepWaves + 3) / 4), dim3(256), 0, stream>>>(
        prox, emb, pn, en, minneg, accum, ticket, C, B);
    gemmmax_kernel<<<dim3((B / 256) * (C / SLAB)), dim3(256), 0, stream>>>(
        en, pn, labels, minneg);
    finalize_kernel<<<dim3((B + 3) / 4), dim3(256), 0, stream>>>(
        emb, prox, labels, minneg, accum, ticket, (float*)d_out, B);
}

// Round 14
// 190.806 us; speedup vs baseline: 1.3140x; 1.0383x over previous
//
#include <hip/hip_runtime.h>
#include <hip/hip_bf16.h>

#define D 128
#define LOSS_MARGIN 0.2f
#define SPB 25                 // 16-col MFMA steps per block
#define SLAB (SPB * 16)        // 400 cols; C = 250 slabs * 400
#define ROWG 16                // 2048 / 128 row-groups
#define CHUNK_BYTES 20480      // 80 cols * 256 B

typedef __attribute__((ext_vector_type(8))) short bf16x8;
typedef __attribute__((ext_vector_type(4))) float f32x4;

static __device__ __forceinline__ unsigned short f2bf(float f) {
    unsigned u = __float_as_uint(f);
    unsigned r = (u + 0x7FFFu + ((u >> 16) & 1u)) >> 16;  // RNE
    return (unsigned short)r;
}

// async global->LDS, 16B per lane; LDS dest wave-uniform base (HW adds lane*16).
static __device__ __forceinline__ void stage16(const void* g, void* l) {
    __builtin_amdgcn_global_load_lds(
        (__attribute__((address_space(1))) void*)g,
        (__attribute__((address_space(3))) void*)l, 16, 0, 0);
}

// Pass A: L2-normalize proxies -> bf16 ; embeddings -> bf16. Linear layout,
// 16B/lane. 4 rows per wave (16 lanes/row). Also inits minneg/accum/ticket.
__global__ void prep_kernel(const float* __restrict__ prox,
                            const float* __restrict__ emb,
                            unsigned short* __restrict__ pn,
                            unsigned short* __restrict__ en,
                            unsigned int* __restrict__ minneg,
                            float* __restrict__ accum,
                            unsigned int* __restrict__ ticket,
                            int C, int B) {
    unsigned gtid = blockIdx.x * blockDim.x + threadIdx.x;
    if (gtid < (unsigned)B) minneg[gtid] = 0xFFFFFFFFu;
    if (gtid == 0) { *accum = 0.f; *ticket = 0u; }

    int wave = blockIdx.x * (blockDim.x >> 6) + (threadIdx.x >> 6);
    int lane = threadIdx.x & 63;
    int sub = lane >> 4;       // which of the wave's 4 rows
    int l16 = lane & 15;
    int row = wave * 4 + sub;
    if (row >= C + B) return;

    const float* src;
    unsigned short* dst;
    bool donorm;
    if (row < C) { src = prox + (size_t)row * D; dst = pn + (size_t)row * D; donorm = true; }
    else { int r = row - C; src = emb + (size_t)r * D; dst = en + (size_t)r * D; donorm = false; }

    float4 v0 = *(const float4*)(src + l16 * 8);
    float4 v1 = *(const float4*)(src + l16 * 8 + 4);
    float scale = 1.f;
    if (donorm) {  // 16-lane-group reduction (xor masks < 16 stay in-group)
        float ss = v0.x * v0.x + v0.y * v0.y + v0.z * v0.z + v0.w * v0.w
                 + v1.x * v1.x + v1.y * v1.y + v1.z * v1.z + v1.w * v1.w;
        #pragma unroll
        for (int m = 1; m < 16; m <<= 1) ss += __shfl_xor(ss, m);
        scale = rsqrtf(ss);
    }
    uint4 pack;
    pack.x = (unsigned)f2bf(v0.x * scale) | ((unsigned)f2bf(v0.y * scale) << 16);
    pack.y = (unsigned)f2bf(v0.z * scale) | ((unsigned)f2bf(v0.w * scale) << 16);
    pack.z = (unsigned)f2bf(v1.x * scale) | ((unsigned)f2bf(v1.y * scale) << 16);
    pack.w = (unsigned)f2bf(v1.z * scale) | ((unsigned)f2bf(v1.w * scale) << 16);
    *(uint4*)(dst + l16 * 8) = pack;
}

// Pass B: fused bf16 GEMM + per-row max over negatives.
// XCD-swizzled 1-D grid (4000 blocks). Block = 4 waves, 128 rows (32/wave —
// r13 post-mortem: 64 rows/wave locked occupancy at 2 waves/SIMD; halving the
// A-fragment footprint (64->32 VGPR) buys 3-4 waves/SIMD of TLP); slab 400 cols.
// B staged via global_load_lds, pre-swizzled source, XOR-swizzled ds_read.
__global__ __launch_bounds__(256, 3) void gemmmax_kernel(
        const unsigned short* __restrict__ en,
        const unsigned short* __restrict__ pn,
        const int* __restrict__ labels,
        unsigned int* __restrict__ minneg) {
    __shared__ char smem[2 * CHUNK_BYTES];   // 40 KiB

    int n = blockIdx.x;
    int chunkg = gridDim.x >> 3;             // 500 per XCD
    int wgid = (n & 7) * chunkg + (n >> 3);
    int slab   = wgid >> 4;                  // /ROWG
    int rowgrp = wgid & (ROWG - 1);

    int lane = threadIdx.x & 63;
    int wid  = threadIdx.x >> 6;
    int wbase = rowgrp * 128 + wid * 32;
    int r16 = lane & 15;
    int g   = lane >> 4;
    int col0 = slab * SLAB;
    int swz = r16 << 4;                      // 4-bit key: conflict-free b128 (r10: 0 conflicts)

    const char* slabSrc = (const char*)pn + (size_t)col0 * (D * 2);
    int stago = wid * 1024 + lane * 16;
    // source-side swizzle: LDS byte o receives global byte with 16B-slot
    // (o>>4)&15 XOR'd by row-in-chunk (o>>8)&15. Invariant under +r*4096 and
    // +t*CHUNK (only bits >=12 change; (row&15) unchanged, 80|16, 400|16).
    int srcswz = (stago & ~0xF0) | (((((stago >> 4) & 15) ^ ((stago >> 8) & 15))) << 4);

#define STAGE_CHUNK(T, BUF)                                                     \
    {                                                                           \
        const char* gs_ = slabSrc + (size_t)((T) * CHUNK_BYTES) + srcswz;       \
        char* ls_ = smem + (BUF) * CHUNK_BYTES + wid * 1024;                    \
        stage16(gs_,          ls_);                                             \
        stage16(gs_ + 4096,   ls_ + 4096);                                      \
        stage16(gs_ + 8192,   ls_ + 8192);                                      \
        stage16(gs_ + 12288,  ls_ + 12288);                                     \
        stage16(gs_ + 16384,  ls_ + 16384);                                     \
    }

    STAGE_CHUNK(0, 0)

    // A fragments: lane l, slot j -> E[row = wbase+s4*16+(l&15)][k = k4*32+(l>>4)*8+j]
    bf16x8 a[2][4];
    #pragma unroll
    for (int s4 = 0; s4 < 2; ++s4)
        #pragma unroll
        for (int k4 = 0; k4 < 4; ++k4)
            a[s4][k4] = *(const bf16x8*)(en + (size_t)(wbase + s4 * 16 + r16) * D + k4 * 32 + g * 8);

    // wave-uniform bitmask of steps containing a positive class
    unsigned bits = 0;
    #pragma unroll
    for (int s4 = 0; s4 < 2; ++s4)
        #pragma unroll
        for (int i = 0; i < 4; ++i) {
            int lb = labels[wbase + s4 * 16 + g * 4 + i];
            int pc = lb - col0;
            if (pc >= 0 && pc < SLAB) bits |= 1u << (pc >> 4);
        }
    #pragma unroll
    for (int m = 1; m < 64; m <<= 1) bits |= __shfl_xor(bits, m);
    unsigned sbits = __builtin_amdgcn_readfirstlane(bits);

    float rm[2][4];
    #pragma unroll
    for (int s4 = 0; s4 < 2; ++s4)
        #pragma unroll
        for (int i = 0; i < 4; ++i) rm[s4][i] = -1e30f;

    const f32x4 zero = {0.f, 0.f, 0.f, 0.f};
    // per-lane LDS base pointers; all step/buffer offsets are immediates.
    // logical 16B slot of read j is (g + 4j); stored slot = (g+4j) ^ r16.
    const char* p0 = smem + r16 * 256 + ((g * 16 + 0)   ^ swz);
    const char* p1 = smem + r16 * 256 + ((g * 16 + 64)  ^ swz);
    const char* p2 = smem + r16 * 256 + ((g * 16 + 128) ^ swz);
    const char* p3 = smem + r16 * 256 + ((g * 16 + 192) ^ swz);

#define MFMA __builtin_amdgcn_mfma_f32_16x16x32_bf16
#define DO_STEP(BASE, STEP)                                                     \
    {                                                                           \
        bf16x8 b0 = *(const bf16x8*)(p0 + (BASE));                              \
        bf16x8 b1 = *(const bf16x8*)(p1 + (BASE));                              \
        bf16x8 b2 = *(const bf16x8*)(p2 + (BASE));                              \
        bf16x8 b3 = *(const bf16x8*)(p3 + (BASE));                              \
        f32x4 cc[2];                                                            \
        _Pragma("unroll")                                                       \
        for (int s4 = 0; s4 < 2; ++s4) cc[s4] = MFMA(a[s4][0], b0, zero, 0, 0, 0); \
        _Pragma("unroll")                                                       \
        for (int s4 = 0; s4 < 2; ++s4) cc[s4] = MFMA(a[s4][1], b1, cc[s4], 0, 0, 0); \
        _Pragma("unroll")                                                       \
        for (int s4 = 0; s4 < 2; ++s4) cc[s4] = MFMA(a[s4][2], b2, cc[s4], 0, 0, 0); \
        _Pragma("unroll")                                                       \
        for (int s4 = 0; s4 < 2; ++s4) cc[s4] = MFMA(a[s4][3], b3, cc[s4], 0, 0, 0); \
        if (__builtin_expect((sbits >> (STEP)) & 1u, 0)) {                      \
            int colg = col0 + (STEP) * 16 + r16;                                \
            _Pragma("unroll")                                                   \
            for (int s4 = 0; s4 < 2; ++s4)                                      \
                _Pragma("unroll")                                               \
                for (int i = 0; i < 4; ++i) {                                   \
                    int lb2 = labels[wbase + s4 * 16 + g * 4 + i];              \
                    float v = (colg == lb2) ? -1e30f : cc[s4][i];               \
                    rm[s4][i] = fmaxf(rm[s4][i], v);                            \
                }                                                               \
        } else {                                                                \
            _Pragma("unroll")                                                   \
            for (int s4 = 0; s4 < 2; ++s4)                                      \
                _Pragma("unroll")                                               \
                for (int i = 0; i < 4; ++i)                                     \
                    rm[s4][i] = fmaxf(rm[s4][i], cc[s4][i]);                    \
        }                                                                       \
    }

#define STEPS5(BASE, T0)                                                        \
    DO_STEP((BASE) + 0,     (T0) + 0)                                           \
    DO_STEP((BASE) + 4096,  (T0) + 1)                                           \
    DO_STEP((BASE) + 8192,  (T0) + 2)                                           \
    DO_STEP((BASE) + 12288, (T0) + 3)                                           \
    DO_STEP((BASE) + 16384, (T0) + 4)

    __syncthreads();                       // chunk 0 resident
    STAGE_CHUNK(1, 1) STEPS5(0, 0)              __syncthreads();
    STAGE_CHUNK(2, 0) STEPS5(CHUNK_BYTES, 5)    __syncthreads();
    STAGE_CHUNK(3, 1) STEPS5(0, 10)             __syncthreads();
    STAGE_CHUNK(4, 0) STEPS5(CHUNK_BYTES, 15)   __syncthreads();
    STEPS5(0, 20)
#undef STEPS5
#undef DO_STEP
#undef MFMA
#undef STAGE_CHUNK

    // reduce max across the 16 lanes of each row-group, combine across blocks
    #pragma unroll
    for (int s4 = 0; s4 < 2; ++s4)
        #pragma unroll
        for (int i = 0; i < 4; ++i) {
            float v = rm[s4][i];
            v = fmaxf(v, __shfl_xor(v, 1));
            v = fmaxf(v, __shfl_xor(v, 2));
            v = fmaxf(v, __shfl_xor(v, 4));
            v = fmaxf(v, __shfl_xor(v, 8));
            if (r16 == 0) {
                int r = wbase + s4 * 16 + g * 4 + i;
                float md = fmaxf(2.f - 2.f * v, 0.f);  // >=0 -> uint order == float order
                atomicMin(minneg + r, __float_as_uint(md));
            }
        }
}

// Pass C: exact fp32 positive distance + per-row loss; last block writes the mean.
__global__ void finalize_kernel(const float* __restrict__ emb,
                                const float* __restrict__ prox,
                                const int* __restrict__ labels,
                                const unsigned int* __restrict__ minneg,
                                float* __restrict__ accum,
                                unsigned int* __restrict__ ticket,
                                float* __restrict__ out, int B) {
    int wave = blockIdx.x * (blockDim.x >> 6) + (threadIdx.x >> 6);
    int lane = threadIdx.x & 63;
    if (wave < B) {
        int lab = labels[wave];
        float2 e = *(const float2*)(emb + (size_t)wave * D + lane * 2);
        float2 p = *(const float2*)(prox + (size_t)lab * D + lane * 2);
        float spp = p.x * p.x + p.y * p.y;
        float sep = e.x * p.x + e.y * p.y;
        #pragma unroll
        for (int m = 1; m < 64; m <<= 1) {
            spp += __shfl_xor(spp, m);
            sep += __shfl_xor(sep, m);
        }
        if (lane == 0) {
            float pos_sim = sep * rsqrtf(spp);
            float pos_dist = 2.f - 2.f * pos_sim;
            float mn = __uint_as_float(minneg[wave]);
            float loss = fmaxf(pos_dist + LOSS_MARGIN - mn, 0.f);
            atomicAdd(accum, loss);
        }
    }
    __threadfence();
    __syncthreads();
    if (threadIdx.x == 0) {
        unsigned old = atomicAdd(ticket, 1u);
        if (old == gridDim.x - 1) {            // last block: all adds visible
            __threadfence();
            float total = atomicAdd(accum, 0.f);   // coherent read
            out[0] = total * (1.f / (float)B);
        }
    }
}

extern "C" void kernel_launch(void* const* d_in, const int* in_sizes, int n_in,
                              void* d_out, int out_size, void* d_ws, size_t ws_size,
                              hipStream_t stream) {
    const float* emb  = (const float*)d_in[0];
    const float* prox = (const float*)d_in[1];
    const int*   labels = (const int*)d_in[2];
    int B = in_sizes[0] / D;  // 2048
    int C = in_sizes[1] / D;  // 100000

    char* ws = (char*)d_ws;
    unsigned short* pn = (unsigned short*)ws;                       // C*D bf16 (LINEAR)
    size_t offEN  = (size_t)C * D * 2 + (size_t)64 * D * 2;
    unsigned short* en = (unsigned short*)(ws + offEN);             // B*D bf16
    size_t offMIN = offEN + (size_t)B * D * 2;
    unsigned int* minneg = (unsigned int*)(ws + offMIN);            // B u32
    size_t offACC = offMIN + (size_t)B * 4;
    float* accum = (float*)(ws + offACC);                           // 1 f32
    unsigned int* ticket = (unsigned int*)(ws + offACC + 64);       // 1 u32

    int totalRows = C + B;
    int prepWaves = (totalRows + 3) / 4;
    prep_kernel<<<dim3((prepWaves + 3) / 4), dim3(256), 0, stream>>>(
        prox, emb, pn, en, minneg, accum, ticket, C, B);
    gemmmax_kernel<<<dim3((B / 128) * (C / SLAB)), dim3(256), 0, stream>>>(
        en, pn, labels, minneg);
    finalize_kernel<<<dim3((B + 3) / 4), dim3(256), 0, stream>>>(
        emb, prox, labels, minneg, accum, ticket, (float*)d_out, B);
}